// Round 1
// baseline (3382.405 us; speedup 1.0000x reference)
//
#include <hip/hip_runtime.h>
#include <math.h>

#define NS 1024   // spins / steps
#define NB 4096   // batch
#define NH 128    // hidden
#define RB 16     // batch rows per block
#define NT 256    // threads per block

__device__ __forceinline__ float fast_tanh(float x) {
    float a = __builtin_fabsf(x);
    float e = __expf(2.0f * a);                       // v_exp_f32 based
    float r = 1.0f - 2.0f * __builtin_amdgcn_rcpf(e + 1.0f);
    return __builtin_copysignf(r, x);                 // safe at |x| large: r -> 1
}

__global__ __launch_bounds__(NT, 1)
void pwf_kernel(const float* __restrict__ data_in,
                const float* __restrict__ W_ih,
                const float* __restrict__ W_hh,
                const float* __restrict__ b_ih,
                const float* __restrict__ b_hh,
                const float* __restrict__ W_lin,
                const float* __restrict__ b_lin,
                float* __restrict__ out)
{
    __shared__ float Wt[NH][NH];     // Wt[k][j] = W_hh[j][k]  (64 KB)
    __shared__ float hbuf[RB][NH];   // hidden state, fp32     (8 KB)
    __shared__ float cvec[2][NH];    // c[s][j] = W_ih[j][s]+b_ih[j]+b_hh[j]
    __shared__ float wlin[2][NH];
    __shared__ int   selbuf[2][RB];  // double-buffered input select per row
    __shared__ int   maskbuf[2][RB]; // 0 = none, 1 = up-mask -> [0,1], 2 = down-mask -> [1,0]

    const int tid = threadIdx.x;
    const int b0  = blockIdx.x * RB;

    // ---- prologue: stage weights ----
    for (int i = tid; i < NH * NH; i += NT) {
        Wt[i & (NH - 1)][i >> 7] = W_hh[i];  // transpose into LDS (one-time cost)
    }
    if (tid < NH) {
        float base = b_ih[tid] + b_hh[tid];
        cvec[0][tid] = W_ih[tid * 2 + 0] + base;
        cvec[1][tid] = W_ih[tid * 2 + 1] + base;
        wlin[0][tid] = W_lin[tid];
        wlin[1][tid] = W_lin[NH + tid];
    }
    for (int i = tid; i < RB * NH; i += NT) {
        hbuf[i >> 7][i & (NH - 1)] = 0.0f;   // h0 = zeros
    }
    int   cntup = 0, cntdn = 0;
    float su_next = 0.0f;
    if (tid < RB) {
        selbuf[0][tid]  = 0;   // step 0 input = init_state [1,0] -> select column 0
        maskbuf[0][tid] = 0;   // output 0 is never masked
        su_next = data_in[(size_t)(b0 + tid) * 2];  // prefetch spin_0 channel-0
    }
    const float bl0 = b_lin[0];
    const float bl1 = b_lin[1];
    __syncthreads();

    // matmul mapping: 2 rows x 4 cols per thread
    const int rg  = tid >> 5;      // 0..7
    const int cg  = tid & 31;      // 0..31
    const int r0  = rg * 2;
    const int j0  = cg * 4;
    // logits mapping: 16 threads per row
    const int rl  = tid >> 4;      // 0..15
    const int l16 = tid & 15;

    for (int t = 0; t < NS; ++t) {
        const int par = t & 1;

        // ---- pre[r][j] = sum_k h[r][k] * Wt[k][j] ----
        float acc0[4] = {0.f, 0.f, 0.f, 0.f};
        float acc1[4] = {0.f, 0.f, 0.f, 0.f};
        #pragma unroll 8
        for (int k = 0; k < NH; k += 4) {
            float4 h0 = *(const float4*)&hbuf[r0][k];       // broadcast across cg lanes
            float4 h1 = *(const float4*)&hbuf[r0 + 1][k];
            float4 w0 = *(const float4*)&Wt[k + 0][j0];     // consecutive -> conflict-free
            float4 w1 = *(const float4*)&Wt[k + 1][j0];
            float4 w2 = *(const float4*)&Wt[k + 2][j0];
            float4 w3 = *(const float4*)&Wt[k + 3][j0];
            acc0[0] += h0.x * w0.x; acc0[1] += h0.x * w0.y; acc0[2] += h0.x * w0.z; acc0[3] += h0.x * w0.w;
            acc1[0] += h1.x * w0.x; acc1[1] += h1.x * w0.y; acc1[2] += h1.x * w0.z; acc1[3] += h1.x * w0.w;
            acc0[0] += h0.y * w1.x; acc0[1] += h0.y * w1.y; acc0[2] += h0.y * w1.z; acc0[3] += h0.y * w1.w;
            acc1[0] += h1.y * w1.x; acc1[1] += h1.y * w1.y; acc1[2] += h1.y * w1.z; acc1[3] += h1.y * w1.w;
            acc0[0] += h0.z * w2.x; acc0[1] += h0.z * w2.y; acc0[2] += h0.z * w2.z; acc0[3] += h0.z * w2.w;
            acc1[0] += h1.z * w2.x; acc1[1] += h1.z * w2.y; acc1[2] += h1.z * w2.z; acc1[3] += h1.z * w2.w;
            acc0[0] += h0.w * w3.x; acc0[1] += h0.w * w3.y; acc0[2] += h0.w * w3.z; acc0[3] += h0.w * w3.w;
            acc1[0] += h1.w * w3.x; acc1[1] += h1.w * w3.y; acc1[2] += h1.w * w3.z; acc1[3] += h1.w * w3.w;
        }

        const int sl0 = selbuf[par][r0];
        const int sl1 = selbuf[par][r0 + 1];
        float hn0[4], hn1[4];
        #pragma unroll
        for (int jj = 0; jj < 4; ++jj) {
            hn0[jj] = fast_tanh(acc0[jj] + cvec[sl0][j0 + jj]);
            hn1[jj] = fast_tanh(acc1[jj] + cvec[sl1][j0 + jj]);
        }

        __syncthreads();   // all reads of old h done
        *(float4*)&hbuf[r0][j0]     = make_float4(hn0[0], hn0[1], hn0[2], hn0[3]);
        *(float4*)&hbuf[r0 + 1][j0] = make_float4(hn1[0], hn1[1], hn1[2], hn1[3]);

        if (tid < RB) {
            // consume data_in[t][b][0] (prefetched last step): input for step t+1,
            // and mask state for output t+1 (cum over spins 0..t)
            int isup = su_next > 0.5f;            // channel0==1 -> spin==0 ("up")
            cntup += isup;
            cntdn += 1 - isup;
            selbuf[par ^ 1][tid]  = 1 - isup;
            maskbuf[par ^ 1][tid] = (cntdn >= NS / 2) ? 2 : ((cntup >= NS / 2) ? 1 : 0);
            int tn = (t + 1 < NS) ? (t + 1) : t;  // clamp (last load unused)
            su_next = data_in[((size_t)tn * NB + b0 + tid) * 2];   // prefetch next
        }
        __syncthreads();   // new h + sel/mask visible

        // ---- logits + softmax + mask + store ----
        float4 ha = *(const float4*)&hbuf[rl][l16 * 8];
        float4 hb = *(const float4*)&hbuf[rl][l16 * 8 + 4];
        float4 wa = *(const float4*)&wlin[0][l16 * 8];
        float4 wb = *(const float4*)&wlin[0][l16 * 8 + 4];
        float4 va = *(const float4*)&wlin[1][l16 * 8];
        float4 vb = *(const float4*)&wlin[1][l16 * 8 + 4];
        float d0 = ha.x * wa.x + ha.y * wa.y + ha.z * wa.z + ha.w * wa.w
                 + hb.x * wb.x + hb.y * wb.y + hb.z * wb.z + hb.w * wb.w;
        float d1 = ha.x * va.x + ha.y * va.y + ha.z * va.z + ha.w * va.w
                 + hb.x * vb.x + hb.y * vb.y + hb.z * vb.z + hb.w * vb.w;
        d0 += __shfl_xor(d0, 1); d0 += __shfl_xor(d0, 2);
        d0 += __shfl_xor(d0, 4); d0 += __shfl_xor(d0, 8);
        d1 += __shfl_xor(d1, 1); d1 += __shfl_xor(d1, 2);
        d1 += __shfl_xor(d1, 4); d1 += __shfl_xor(d1, 8);
        if (l16 == 0) {
            float l0 = d0 + bl0;
            float l1 = d1 + bl1;
            float p0 = __builtin_amdgcn_rcpf(1.0f + __expf(l1 - l0));  // softmax 2-class
            float p1 = 1.0f - p0;
            int mk = maskbuf[par][rl];
            if (mk) { p0 = (mk == 2) ? 1.0f : 0.0f; p1 = 1.0f - p0; }  // down overrides up
            *(float2*)&out[((size_t)t * NB + (b0 + rl)) * 2] = make_float2(p0, p1);
        }
    }
}

extern "C" void kernel_launch(void* const* d_in, const int* in_sizes, int n_in,
                              void* d_out, int out_size, void* d_ws, size_t ws_size,
                              hipStream_t stream) {
    const float* data_in = (const float*)d_in[0];
    const float* W_ih    = (const float*)d_in[1];
    const float* W_hh    = (const float*)d_in[2];
    const float* b_ih    = (const float*)d_in[3];
    const float* b_hh    = (const float*)d_in[4];
    const float* W_lin   = (const float*)d_in[5];
    const float* b_lin   = (const float*)d_in[6];
    float* out = (float*)d_out;

    dim3 grid(NB / RB);   // 256 blocks, one per CU
    dim3 block(NT);
    pwf_kernel<<<grid, block, 0, stream>>>(data_in, W_ih, W_hh, b_ih, b_hh,
                                           W_lin, b_lin, out);
}

// Round 2
// 656.810 us; speedup vs baseline: 5.1497x; 5.1497x over previous
//
#include <hip/hip_runtime.h>
#include <hip/hip_bf16.h>

#define NS 1024   // spins / steps
#define NB 4096   // batch
#define NH 128    // hidden
#define RB 16     // batch rows per block
#define NT 512    // threads per block (8 waves)

typedef __attribute__((ext_vector_type(8))) short short8;
typedef __attribute__((ext_vector_type(4))) float f32x4;

__device__ __forceinline__ float fast_tanh(float x) {
    float a = __builtin_fabsf(x);
    float e = __expf(2.0f * a);
    float r = 1.0f - 2.0f * __builtin_amdgcn_rcpf(e + 1.0f);
    return __builtin_copysignf(r, x);
}
__device__ __forceinline__ short f2bf(float x) {   // fp32 -> bf16 RNE
    unsigned u = __builtin_bit_cast(unsigned, x);
    u = (u + 0x7FFFu + ((u >> 16) & 1u)) >> 16;
    return (short)u;
}
__device__ __forceinline__ float bf2f(short s) {
    unsigned u = ((unsigned)(unsigned short)s) << 16;
    return __builtin_bit_cast(float, u);
}

__global__ __launch_bounds__(NT, 1)
void pwf_kernel(const float* __restrict__ data_in,
                const float* __restrict__ W_ih,
                const float* __restrict__ W_hh,
                const float* __restrict__ b_ih,
                const float* __restrict__ b_hh,
                const float* __restrict__ W_lin,
                const float* __restrict__ b_lin,
                float* __restrict__ out)
{
    // bf16 hidden state, double-buffered, XOR-swizzled at 8-elem (16B) granules:
    // elem(row,col) -> row*128 + (((col>>3) ^ (row&7))*8) + (col&7)
    __shared__ __align__(16) short hlds[2][RB * NH];   // 8 KB
    __shared__ unsigned selm[2], upm[2], dnm[2];

    const int tid = threadIdx.x;
    const int w   = tid >> 6;       // wave 0..7
    const int l   = tid & 63;       // lane
    const int g   = l >> 4;         // k-group 0..3
    const int n16 = l & 15;         // A-row / B-col within tile
    const int b0  = blockIdx.x * RB;

    // ---- B fragments: W_hh rows held in registers forever ----
    // B[k][n] for tile cols j0=w*16: lane holds Wt[k][j0+n16] = W_hh[j0+n16][k],
    // k = kb*32 + g*8 + i  (8 contiguous fp32 in W_hh's row -> vector load)
    const int col = w * 16 + n16;          // 0..127
    short8 bfrag[4];
    #pragma unroll
    for (int kb = 0; kb < 4; ++kb) {
        const float* src = W_hh + col * NH + kb * 32 + g * 8;
        float4 f0 = *(const float4*)(src);
        float4 f1 = *(const float4*)(src + 4);
        short8 v;
        v[0] = f2bf(f0.x); v[1] = f2bf(f0.y); v[2] = f2bf(f0.z); v[3] = f2bf(f0.w);
        v[4] = f2bf(f1.x); v[5] = f2bf(f1.y); v[6] = f2bf(f1.z); v[7] = f2bf(f1.w);
        bfrag[kb] = v;
    }
    // per-col input contribution (one-hot -> select), fp32 in regs
    const float cb  = b_ih[col] + b_hh[col];
    const float cv0 = W_ih[col * 2 + 0] + cb;
    const float cv1 = W_ih[col * 2 + 1] + cb;

    // A-read element offsets (swizzled), per kb
    int aoff[4];
    #pragma unroll
    for (int kb = 0; kb < 4; ++kb)
        aoff[kb] = n16 * NH + (((kb * 4 + g) ^ (n16 & 7)) * 8);
    // h-write element offsets, per C-reg r (row = g*4+r, col fixed)
    int woff[4];
    #pragma unroll
    for (int r = 0; r < 4; ++r) {
        int row = g * 4 + r;
        woff[r] = row * NH + (((col >> 3) ^ (row & 7)) * 8) + (col & 7);
    }

    // ---- logits setup (waves 0..3 = tid<256: 16 lanes per batch row) ----
    const int rl  = tid >> 4;   // row 0..15 (valid for tid<256)
    const int i16 = tid & 15;
    const int loff = (rl & 15) * NH + ((i16 ^ (rl & 7)) * 8);
    float wl0[8], wl1[8];
    #pragma unroll
    for (int i = 0; i < 8; ++i) {
        wl0[i] = W_lin[i16 * 8 + i];
        wl1[i] = W_lin[NH + i16 * 8 + i];
    }
    const float bl0 = b_lin[0];
    const float bl1 = b_lin[1];

    // ---- init: zero h[0], zero masks, prefetch spin 0 (wave 7) ----
    *(uint2*)&hlds[0][tid * 4] = make_uint2(0u, 0u);   // 512 thr * 4 shorts = 2048
    if (tid == 0) { selm[0] = 0u; upm[0] = 0u; dnm[0] = 0u; }
    int cntup = 0, cntdn = 0;
    float su_next = 0.0f;
    if (w == 7) {
        int rr = (l < RB) ? l : (RB - 1);
        su_next = data_in[(size_t)(b0 + rr) * 2];
    }
    __syncthreads();

    for (int t = 0; t < NS; ++t) {
        const int p = t & 1;
        const short* hr = hlds[p];
        short* hw = hlds[p ^ 1];

        // ---- phase 1: recurrence ----
        const unsigned sel = selm[p];                 // input select bits for this step
        const unsigned um  = upm[p], dm = dnm[p];     // output-mask bits for this step

        short8 a0 = *(const short8*)&hr[aoff[0]];
        short8 a1 = *(const short8*)&hr[aoff[1]];
        short8 a2 = *(const short8*)&hr[aoff[2]];
        short8 a3 = *(const short8*)&hr[aoff[3]];
        f32x4 c = {0.f, 0.f, 0.f, 0.f};
        c = __builtin_amdgcn_mfma_f32_16x16x32_bf16(a0, bfrag[0], c, 0, 0, 0);
        c = __builtin_amdgcn_mfma_f32_16x16x32_bf16(a1, bfrag[1], c, 0, 0, 0);
        c = __builtin_amdgcn_mfma_f32_16x16x32_bf16(a2, bfrag[2], c, 0, 0, 0);
        c = __builtin_amdgcn_mfma_f32_16x16x32_bf16(a3, bfrag[3], c, 0, 0, 0);

        #pragma unroll
        for (int r = 0; r < 4; ++r) {
            const int row = g * 4 + r;                 // C layout: col=lane&15, row=(lane>>4)*4+r
            const float cv = ((sel >> row) & 1u) ? cv1 : cv0;
            const float hn = fast_tanh(c[r] + cv);
            hw[woff[r]] = f2bf(hn);
        }

        // ---- wave 7: spin consume + masks for t+1 + prefetch ----
        if (w == 7) {
            const int isup = (su_next > 0.5f) ? 1 : 0;   // channel0==1 -> spin==0
            cntup += isup;
            cntdn += 1 - isup;
            unsigned long long bsel = __ballot(isup == 0);        // sel = spin value
            unsigned long long bup  = __ballot(cntup >= NS / 2);
            unsigned long long bdn  = __ballot(cntdn >= NS / 2);
            if (l == 0) {
                selm[p ^ 1] = (unsigned)bsel & 0xFFFFu;
                upm[p ^ 1]  = (unsigned)bup  & 0xFFFFu;
                dnm[p ^ 1]  = (unsigned)bdn  & 0xFFFFu;
            }
            const int tn = (t + 1 < NS) ? (t + 1) : t;
            const int rr = (l < RB) ? l : (RB - 1);
            su_next = data_in[((size_t)tn * NB + b0 + rr) * 2];
        }
        __syncthreads();

        // ---- phase 2: logits + softmax + mask + store (waves 0..3) ----
        if (tid < 256) {
            const short8 hv = *(const short8*)&hw[loff];
            float d0 = 0.f, d1 = 0.f;
            #pragma unroll
            for (int i = 0; i < 8; ++i) {
                const float hf = bf2f(hv[i]);
                d0 += hf * wl0[i];
                d1 += hf * wl1[i];
            }
            d0 += __shfl_xor(d0, 1); d0 += __shfl_xor(d0, 2);
            d0 += __shfl_xor(d0, 4); d0 += __shfl_xor(d0, 8);
            d1 += __shfl_xor(d1, 1); d1 += __shfl_xor(d1, 2);
            d1 += __shfl_xor(d1, 4); d1 += __shfl_xor(d1, 8);
            if (i16 == 0) {
                float p0 = __builtin_amdgcn_rcpf(1.0f + __expf((d1 + bl1) - (d0 + bl0)));
                float p1 = 1.0f - p0;
                if ((um >> rl) & 1u) { p0 = 0.0f; p1 = 1.0f; }
                if ((dm >> rl) & 1u) { p0 = 1.0f; p1 = 0.0f; }   // down overrides up
                *(float2*)&out[((size_t)t * NB + b0 + rl) * 2] = make_float2(p0, p1);
            }
        }
    }
}

extern "C" void kernel_launch(void* const* d_in, const int* in_sizes, int n_in,
                              void* d_out, int out_size, void* d_ws, size_t ws_size,
                              hipStream_t stream) {
    const float* data_in = (const float*)d_in[0];
    const float* W_ih    = (const float*)d_in[1];
    const float* W_hh    = (const float*)d_in[2];
    const float* b_ih    = (const float*)d_in[3];
    const float* b_hh    = (const float*)d_in[4];
    const float* W_lin   = (const float*)d_in[5];
    const float* b_lin   = (const float*)d_in[6];
    float* out = (float*)d_out;

    dim3 grid(NB / RB);   // 256 blocks, one per CU
    dim3 block(NT);       // 8 waves
    pwf_kernel<<<grid, block, 0, stream>>>(data_in, W_ih, W_hh, b_ih, b_hh,
                                           W_lin, b_lin, out);
}

// Round 3
// 554.613 us; speedup vs baseline: 6.0987x; 1.1843x over previous
//
#include <hip/hip_runtime.h>

#define NS 1024   // spins / steps
#define NB 4096   // batch
#define NH 128    // hidden
#define RB 16     // batch rows per block
#define NT 512    // threads per block (8 waves)

typedef __attribute__((ext_vector_type(8))) short short8;
typedef __attribute__((ext_vector_type(4))) float f32x4;

__device__ __forceinline__ short f2bf(float x) {   // fp32 -> bf16 RNE
    unsigned u = __builtin_bit_cast(unsigned, x);
    u = (u + 0x7FFFu + ((u >> 16) & 1u)) >> 16;
    return (short)u;
}

__global__ __launch_bounds__(NT, 1)
void pwf_kernel(const float* __restrict__ data_in,
                const float* __restrict__ W_ih,
                const float* __restrict__ W_hh,
                const float* __restrict__ b_ih,
                const float* __restrict__ b_hh,
                const float* __restrict__ W_lin,
                const float* __restrict__ b_lin,
                float* __restrict__ out)
{
    // bf16 h, double-buffered, row-major [row][col], XOR-swizzled 8-elem granules:
    // elem(row,col) -> row*128 + (((col>>3) ^ (row>>1))*8) + (col&7)
    // (row>>1 gives 4 distinct granule shifts across the 4 lane-groups of one
    //  ds_write -> 8 granules -> 32 banks at 2 lanes/bank = conflict-free)
    __shared__ __align__(16) short hlds[2][RB * NH];   // 8 KB
    __shared__ unsigned selm[2];       // input-select bits, 2-deep
    __shared__ unsigned upm[4], dnm[4];// output masks, 4-deep (logits lag 1 step)

    const int tid = threadIdx.x;
    const int w   = tid >> 6;       // wave 0..7
    const int l   = tid & 63;       // lane
    const int g   = l >> 4;         // k-group 0..3
    const int n16 = l & 15;         // A-row / B-col within tile
    const int b0  = blockIdx.x * RB;

    // ---- B fragments: W_hh held in registers forever ----
    const int col = w * 16 + n16;          // 0..127
    short8 bfrag[4];
    #pragma unroll
    for (int kb = 0; kb < 4; ++kb) {
        const float* src = W_hh + col * NH + kb * 32 + g * 8;
        short8 v;
        #pragma unroll
        for (int i = 0; i < 8; ++i) v[i] = f2bf(src[i]);
        bfrag[kb] = v;
    }
    // ---- logit B-fragments (used by wave 0): col0 = W_lin[0], col1 = W_lin[1] ----
    short8 lfrag[4];
    #pragma unroll
    for (int kb = 0; kb < 4; ++kb) {
        short8 v;
        #pragma unroll
        for (int i = 0; i < 8; ++i) {
            const int k = kb * 32 + g * 8 + i;
            const float x = (n16 == 0) ? W_lin[k] : ((n16 == 1) ? W_lin[NH + k] : 0.0f);
            v[i] = f2bf(x);
        }
        lfrag[kb] = v;
    }

    // per-col input contribution, pre-scaled by 2 for tanh(x)=1-2/(exp(2x)+1)
    const float cb  = b_ih[col] + b_hh[col];
    const float cv0 = 2.0f * (W_ih[col * 2 + 0] + cb);
    const float cv1 = 2.0f * (W_ih[col * 2 + 1] + cb);
    const float bl0 = b_lin[0];
    const float bl1 = b_lin[1];

    // A-read offsets (short index), conflict-free granule swizzle
    int aoff[4];
    #pragma unroll
    for (int kb = 0; kb < 4; ++kb)
        aoff[kb] = n16 * NH + (((kb * 4 + g) ^ (n16 >> 1)) * 8);
    // h-write offsets per C-reg r (row = g*4+r, col fixed)
    int woff[4];
    #pragma unroll
    for (int r = 0; r < 4; ++r) {
        const int row = g * 4 + r;
        woff[r] = row * NH + (((col >> 3) ^ (row >> 1)) * 8) + (col & 7);
    }

    // ---- init ----
    *(uint2*)&hlds[0][tid * 4] = make_uint2(0u, 0u);   // h0 = 0
    if (tid == 0) { selm[0] = 0u; upm[0] = 0u; dnm[0] = 0u; }
    int cntup = 0, cntdn = 0;
    float su_next = 0.0f;
    if (w == 7) {
        const int rr = (l < RB) ? l : (RB - 1);
        su_next = data_in[(size_t)(b0 + rr) * 2];
    }
    __syncthreads();

    for (int t = 0; t < NS; ++t) {
        const int p = t & 1;
        const short* hr = hlds[p];
        short* hw = hlds[p ^ 1];

        const unsigned sel = selm[p];

        const short8 a0 = *(const short8*)&hr[aoff[0]];
        const short8 a1 = *(const short8*)&hr[aoff[1]];
        const short8 a2 = *(const short8*)&hr[aoff[2]];
        const short8 a3 = *(const short8*)&hr[aoff[3]];

        // ---- wave 0: logits for output t-1 from h_t fragments (matrix pipe) ----
        if (w == 0 && t > 0) {
            f32x4 cl = {0.f, 0.f, 0.f, 0.f};
            cl = __builtin_amdgcn_mfma_f32_16x16x32_bf16(a0, lfrag[0], cl, 0, 0, 0);
            cl = __builtin_amdgcn_mfma_f32_16x16x32_bf16(a1, lfrag[1], cl, 0, 0, 0);
            cl = __builtin_amdgcn_mfma_f32_16x16x32_bf16(a2, lfrag[2], cl, 0, 0, 0);
            cl = __builtin_amdgcn_mfma_f32_16x16x32_bf16(a3, lfrag[3], cl, 0, 0, 0);
            float oth[4];
            #pragma unroll
            for (int r = 0; r < 4; ++r) oth[r] = __shfl_xor(cl[r], 1);
            if (n16 == 0) {   // lanes 0,16,32,48 hold d0; partner lane holds d1
                const unsigned um = upm[(t - 1) & 3];
                const unsigned dm = dnm[(t - 1) & 3];
                #pragma unroll
                for (int r = 0; r < 4; ++r) {
                    const int row = g * 4 + r;
                    float p0 = __builtin_amdgcn_rcpf(
                        1.0f + __expf((oth[r] + bl1) - (cl[r] + bl0)));
                    float p1 = 1.0f - p0;
                    if ((um >> row) & 1u) { p0 = 0.0f; p1 = 1.0f; }
                    if ((dm >> row) & 1u) { p0 = 1.0f; p1 = 0.0f; }  // down overrides
                    *(float2*)&out[((size_t)(t - 1) * NB + b0 + row) * 2] =
                        make_float2(p0, p1);
                }
            }
        }

        // ---- recurrence ----
        f32x4 c = {0.f, 0.f, 0.f, 0.f};
        c = __builtin_amdgcn_mfma_f32_16x16x32_bf16(a0, bfrag[0], c, 0, 0, 0);
        c = __builtin_amdgcn_mfma_f32_16x16x32_bf16(a1, bfrag[1], c, 0, 0, 0);
        c = __builtin_amdgcn_mfma_f32_16x16x32_bf16(a2, bfrag[2], c, 0, 0, 0);
        c = __builtin_amdgcn_mfma_f32_16x16x32_bf16(a3, bfrag[3], c, 0, 0, 0);

        const unsigned nib = (sel >> (g * 4)) & 0xFu;   // this lane's 4 row-sel bits
        float hn[4];
        #pragma unroll
        for (int r = 0; r < 4; ++r) {
            const float cv = (nib & (1u << r)) ? cv1 : cv0;
            const float e  = __expf(fmaf(c[r], 2.0f, cv));
            hn[r] = 1.0f - 2.0f * __builtin_amdgcn_rcpf(e + 1.0f);  // tanh, all x
        }
        unsigned pk01, pk23;
        asm("v_cvt_pk_bf16_f32 %0, %1, %2" : "=v"(pk01) : "v"(hn[0]), "v"(hn[1]));
        asm("v_cvt_pk_bf16_f32 %0, %1, %2" : "=v"(pk23) : "v"(hn[2]), "v"(hn[3]));
        hw[woff[0]] = (short)(pk01 & 0xFFFFu);
        hw[woff[1]] = (short)(pk01 >> 16);
        hw[woff[2]] = (short)(pk23 & 0xFFFFu);
        hw[woff[3]] = (short)(pk23 >> 16);

        // ---- wave 7: spin consume + sel/masks + prefetch ----
        if (w == 7) {
            const int isup = (su_next > 0.5f) ? 1 : 0;   // channel0==1 -> spin==0
            cntup += isup;
            cntdn += 1 - isup;
            const unsigned long long bsel = __ballot(isup == 0);
            const unsigned long long bup  = __ballot(cntup >= NS / 2);
            const unsigned long long bdn  = __ballot(cntdn >= NS / 2);
            if (l == 0) {
                selm[p ^ 1]      = (unsigned)bsel & 0xFFFFu;  // for step t+1
                upm[(t + 1) & 3] = (unsigned)bup  & 0xFFFFu;  // for output t+1
                dnm[(t + 1) & 3] = (unsigned)bdn  & 0xFFFFu;
            }
            const int tn = (t + 1 < NS) ? (t + 1) : t;
            const int rr = (l < RB) ? l : (RB - 1);
            su_next = data_in[((size_t)tn * NB + b0 + rr) * 2];
        }
        __syncthreads();
    }

    // ---- epilogue: output NS-1 from h_NS (sits in hlds[0] after t=1023) ----
    if (w == 0) {
        const short* hr = hlds[0];
        const short8 a0 = *(const short8*)&hr[aoff[0]];
        const short8 a1 = *(const short8*)&hr[aoff[1]];
        const short8 a2 = *(const short8*)&hr[aoff[2]];
        const short8 a3 = *(const short8*)&hr[aoff[3]];
        f32x4 cl = {0.f, 0.f, 0.f, 0.f};
        cl = __builtin_amdgcn_mfma_f32_16x16x32_bf16(a0, lfrag[0], cl, 0, 0, 0);
        cl = __builtin_amdgcn_mfma_f32_16x16x32_bf16(a1, lfrag[1], cl, 0, 0, 0);
        cl = __builtin_amdgcn_mfma_f32_16x16x32_bf16(a2, lfrag[2], cl, 0, 0, 0);
        cl = __builtin_amdgcn_mfma_f32_16x16x32_bf16(a3, lfrag[3], cl, 0, 0, 0);
        float oth[4];
        #pragma unroll
        for (int r = 0; r < 4; ++r) oth[r] = __shfl_xor(cl[r], 1);
        if (n16 == 0) {
            const unsigned um = upm[(NS - 1) & 3];
            const unsigned dm = dnm[(NS - 1) & 3];
            #pragma unroll
            for (int r = 0; r < 4; ++r) {
                const int row = g * 4 + r;
                float p0 = __builtin_amdgcn_rcpf(
                    1.0f + __expf((oth[r] + bl1) - (cl[r] + bl0)));
                float p1 = 1.0f - p0;
                if ((um >> row) & 1u) { p0 = 0.0f; p1 = 1.0f; }
                if ((dm >> row) & 1u) { p0 = 1.0f; p1 = 0.0f; }
                *(float2*)&out[((size_t)(NS - 1) * NB + b0 + row) * 2] =
                    make_float2(p0, p1);
            }
        }
    }
}

extern "C" void kernel_launch(void* const* d_in, const int* in_sizes, int n_in,
                              void* d_out, int out_size, void* d_ws, size_t ws_size,
                              hipStream_t stream) {
    const float* data_in = (const float*)d_in[0];
    const float* W_ih    = (const float*)d_in[1];
    const float* W_hh    = (const float*)d_in[2];
    const float* b_ih    = (const float*)d_in[3];
    const float* b_hh    = (const float*)d_in[4];
    const float* W_lin   = (const float*)d_in[5];
    const float* b_lin   = (const float*)d_in[6];
    float* out = (float*)d_out;

    dim3 grid(NB / RB);   // 256 blocks, one per CU
    dim3 block(NT);       // 8 waves
    pwf_kernel<<<grid, block, 0, stream>>>(data_in, W_ih, W_hh, b_ih, b_hh,
                                           W_lin, b_lin, out);
}